// Round 11
// baseline (286.051 us; speedup 1.0000x reference)
//
#include <hip/hip_runtime.h>
#include <math.h>

#define S_LEN 2048
#define DM 1024
#define NH 16
#define HD 64
#define DFF 4096
#define MROWS 4096  // S_LEN * 2 batch

typedef unsigned short u16;
typedef __attribute__((ext_vector_type(8))) __bf16 bf16x8;
typedef __attribute__((ext_vector_type(4))) float f32x4;
typedef __attribute__((ext_vector_type(16))) float f32x16;
typedef __attribute__((ext_vector_type(4))) int int32x4;

__device__ __forceinline__ u16 f2bf(float f) {
  unsigned u = __float_as_uint(f);
  unsigned r = (u + 0x7fffu + ((u >> 16) & 1u)) >> 16;  // RNE
  return (u16)r;
}

__device__ __forceinline__ float bf2f(u16 u) {
  return __uint_as_float((unsigned)u << 16);
}

__device__ __forceinline__ unsigned cvtpk_bf16(float lo, float hi) {
  unsigned r;
  asm("v_cvt_pk_bf16_f32 %0, %1, %2" : "=v"(r) : "v"(lo), "v"(hi));
  return r;
}

__device__ __forceinline__ void gload_lds16(const void* g, void* l) {
  __builtin_amdgcn_global_load_lds((__attribute__((address_space(1))) void*)g,
                                   (__attribute__((address_space(3))) void*)l, 16, 0, 0);
}

// ---------- fused preprocessing: 6 weight transposes (fp32->bf16) + src f2bf ----------
__global__ __launch_bounds__(256) void k_prep(const float* __restrict__ Wq, const float* __restrict__ Wk,
                                              const float* __restrict__ Wv, const float* __restrict__ Wo,
                                              const float* __restrict__ W1, const float* __restrict__ W2,
                                              u16* __restrict__ Wq_t, u16* __restrict__ Wk_t,
                                              u16* __restrict__ Wv_t, u16* __restrict__ Wo_t,
                                              u16* __restrict__ W1_t, u16* __restrict__ W2_t,
                                              const float4* __restrict__ src4, ushort4* __restrict__ Xbf4) {
  int flat = blockIdx.x;
  if (flat >= 12288) {
    int i = (flat - 12288) * 256 + threadIdx.x;
    float4 v = src4[i];
    ushort4 o;
    o.x = f2bf(v.x); o.y = f2bf(v.y); o.z = f2bf(v.z); o.w = f2bf(v.w);
    Xbf4[i] = o;
    return;
  }
  __shared__ float tile[32][33];
  const float* W;
  u16* Wt;
  int local, nx, K, N;
  if (flat < 4096) {
    int z = flat >> 10;
    W = z == 0 ? Wq : z == 1 ? Wk : z == 2 ? Wv : Wo;
    Wt = z == 0 ? Wq_t : z == 1 ? Wk_t : z == 2 ? Wv_t : Wo_t;
    local = flat & 1023; nx = 32; K = 1024; N = 1024;
  } else if (flat < 8192) {
    W = W1; Wt = W1_t; local = flat - 4096; nx = 128; K = 1024; N = 4096;
  } else {
    W = W2; Wt = W2_t; local = flat - 8192; nx = 32; K = 4096; N = 1024;
  }
  int n0 = (local % nx) * 32, k0 = (local / nx) * 32;
  int tx = threadIdx.x & 31, ty = threadIdx.x >> 5;
  #pragma unroll
  for (int r = ty; r < 32; r += 8) tile[r][tx] = W[(size_t)(k0 + r) * N + n0 + tx];
  __syncthreads();
  #pragma unroll
  for (int r = ty; r < 32; r += 8) Wt[(size_t)(n0 + r) * K + k0 + tx] = f2bf(tile[tx][r]);
}

// ---------- fused misc: rope cos/sin table + bias concat + mask tile flags ----------
__global__ __launch_bounds__(256) void k_misc(float* __restrict__ cosT, float* __restrict__ sinT,
                                              const float* __restrict__ bq, const float* __restrict__ bk,
                                              const float* __restrict__ bv, float* __restrict__ bqkv,
                                              const float* __restrict__ mask,
                                              unsigned char* __restrict__ flags) {
  int flat = blockIdx.x;
  if (flat < 256) {
    int idx = flat * 256 + threadIdx.x;
    int s = idx >> 5, i = idx & 31;
    float inv = powf(10000.f, -(float)(2 * i) / 64.f);
    float ang = (float)s * inv;
    cosT[idx] = cosf(ang);
    sinT[idx] = sinf(ang);
    return;
  }
  if (flat < 268) {
    int i = (flat - 256) * 256 + threadIdx.x;
    if (i < 3072) bqkv[i] = i < 1024 ? bq[i] : (i < 2048 ? bk[i - 1024] : bv[i - 2048]);
    return;
  }
  int local = flat - 268;
  int kt = local & 31, qt = local >> 5;
  const float* mp = mask + (size_t)(qt * 64) * S_LEN + kt * 64;
  int tr = threadIdx.x >> 2;
  int tc = (threadIdx.x & 3) * 16;
  int ok = 1;
  #pragma unroll
  for (int c = 0; c < 16; c += 4) {
    float4 v = *(const float4*)(mp + (size_t)tr * S_LEN + tc + c);
    ok &= (v.x >= 0.1f) & (v.y >= 0.1f) & (v.z >= 0.1f) & (v.w >= 0.1f);
  }
  ok = __all(ok) ? 1 : 0;
  __shared__ int sh[4];
  if ((threadIdx.x & 63) == 0) sh[threadIdx.x >> 6] = ok;
  __syncthreads();
  if (threadIdx.x == 0) flags[qt * 32 + kt] = (sh[0] & sh[1] & sh[2] & sh[3]) ? 0 : 1;
}

// ---------- 256x256-tile pipelined bf16 GEMM ----------
enum { EPI_F32 = 0, EPI_RELU_BF16 = 2, EPI_PARTB = 4, EPI_BF16 = 5 };

template <int EPI>
__global__ __launch_bounds__(512, 2) void k_gemm256(const u16* __restrict__ A,
                                                    const u16* __restrict__ Bt,
                                                    const float* __restrict__ bias,
                                                    float* __restrict__ Cf, u16* __restrict__ Cb,
                                                    int M, int N, int K, int ldc, int Kc) {
  __shared__ __attribute__((aligned(16))) u16 As[4][256 * 32];
  __shared__ __attribute__((aligned(16))) u16 Bs[4][256 * 32];

  int nx = gridDim.x;
  int nwg = nx * gridDim.y;
  int flat = blockIdx.y * nx + blockIdx.x;
  int id = (flat & 7) * (nwg >> 3) + (flat >> 3);
  int n0 = (id % nx) * 256;
  int m0 = (id / nx) * 256;
  int kz = blockIdx.z * Kc;

  int tid = threadIdx.x;
  int lane = tid & 63, w = tid >> 6;
  int wm = (w >> 2) * 128, wn = (w & 3) * 64;
  int l15 = lane & 15, l4 = lane >> 4;
  int NT = Kc >> 5;

  const u16* aS[2];
  const u16* bS[2];
  int dslot[2];
  #pragma unroll
  for (int j = 0; j < 2; ++j) {
    int P = j * 512 + tid;
    int r = P >> 2;
    int sl = (P & 3) ^ (r & 3);
    aS[j] = A + (size_t)(m0 + r) * K + kz + sl * 8;
    bS[j] = Bt + (size_t)(n0 + r) * K + kz + sl * 8;
    dslot[j] = j * 512 + w * 64;
  }

  f32x4 acc[8][4] = {};

  #pragma unroll
  for (int t = 0; t < 3; ++t) {
    #pragma unroll
    for (int j = 0; j < 2; ++j) {
      gload_lds16(aS[j] + t * 32, &As[t][dslot[j] * 8]);
      gload_lds16(bS[j] + t * 32, &Bs[t][dslot[j] * 8]);
    }
  }

  for (int t = 0; t < NT; ++t) {
    int buf = t & 3;
    if (t < NT - 2) asm volatile("s_waitcnt vmcnt(8)" ::: "memory");
    else if (t == NT - 2) asm volatile("s_waitcnt vmcnt(4)" ::: "memory");
    else asm volatile("s_waitcnt vmcnt(0)" ::: "memory");
    __builtin_amdgcn_s_barrier();

    if (t + 3 < NT) {
      int tn = t + 3;
      int bn = tn & 3;
      #pragma unroll
      for (int j = 0; j < 2; ++j) {
        gload_lds16(aS[j] + tn * 32, &As[bn][dslot[j] * 8]);
        gload_lds16(bS[j] + tn * 32, &Bs[bn][dslot[j] * 8]);
      }
    }

    bf16x8 af[8], bq[4];
    #pragma unroll
    for (int m = 0; m < 8; ++m) {
      int r = wm + m * 16 + l15;
      af[m] = *(const bf16x8*)&As[buf][r * 32 + (l4 ^ (r & 3)) * 8];
    }
    #pragma unroll
    for (int n = 0; n < 4; ++n) {
      int r = wn + n * 16 + l15;
      bq[n] = *(const bf16x8*)&Bs[buf][r * 32 + (l4 ^ (r & 3)) * 8];
    }
    __builtin_amdgcn_s_setprio(1);
    #pragma unroll
    for (int m = 0; m < 8; ++m)
      #pragma unroll
      for (int n = 0; n < 4; ++n)
        acc[m][n] = __builtin_amdgcn_mfma_f32_16x16x32_bf16(af[m], bq[n], acc[m][n], 0, 0, 0);
    __builtin_amdgcn_s_setprio(0);
  }

  size_t zoff = (size_t)blockIdx.z * M * ldc;
  #pragma unroll
  for (int m = 0; m < 8; ++m) {
    #pragma unroll
    for (int n = 0; n < 4; ++n) {
      int col = n0 + wn + n * 16 + l15;
      float bv = (EPI == EPI_PARTB) ? 0.f : bias[col];
      #pragma unroll
      for (int r = 0; r < 4; ++r) {
        int row = m0 + wm + m * 16 + l4 * 4 + r;
        float v = acc[m][n][r] + bv;
        size_t o = (size_t)row * ldc + col;
        if (EPI == EPI_F32) Cf[o] = v;
        else if (EPI == EPI_RELU_BF16) Cb[o] = f2bf(fmaxf(v, 0.f));
        else if (EPI == EPI_BF16) Cb[o] = f2bf(v);
        else Cb[zoff + o] = f2bf(v);
      }
    }
  }
}

// ---------- RoPE + head-split, vectorized; V transposed through LDS ----------
#define QSCALE 0.180336881f
__global__ __launch_bounds__(256) void k_rope_heads(const u16* __restrict__ QKVb,
                                                    const float* __restrict__ cosT,
                                                    const float* __restrict__ sinT,
                                                    u16* __restrict__ Qh, u16* __restrict__ Kh,
                                                    u16* __restrict__ Vt) {
  __shared__ u16 Vlds[64 * 80];
  int bh = blockIdx.y;
  int s0 = blockIdx.x * 64;
  int b = bh >> 4, h = bh & 15;
  int tid = threadIdx.x;
  int sr = tid >> 2, dg = (tid & 3) * 16;
  int s = s0 + sr;
  size_t rowbase = (size_t)(s * 2 + b) * 3072 + h * 64 + dg;

  float4 c0 = *(const float4*)&cosT[s * 32 + (dg >> 1)];
  float4 c1 = *(const float4*)&cosT[s * 32 + (dg >> 1) + 4];
  float4 sn0 = *(const float4*)&sinT[s * 32 + (dg >> 1)];
  float4 sn1 = *(const float4*)&sinT[s * 32 + (dg >> 1) + 4];
  float cs[8] = {c0.x, c0.y, c0.z, c0.w, c1.x, c1.y, c1.z, c1.w};
  float sn[8] = {sn0.x, sn0.y, sn0.z, sn0.w, sn1.x, sn1.y, sn1.z, sn1.w};

  {
    uint4 a = *(const uint4*)&QKVb[rowbase];
    uint4 bbu = *(const uint4*)&QKVb[rowbase + 8];
    unsigned ws[8] = {a.x, a.y, a.z, a.w, bbu.x, bbu.y, bbu.z, bbu.w};
    unsigned o[8];
    #pragma unroll
    for (int j = 0; j < 8; ++j) {
      float lo = bf2f((u16)(ws[j] & 0xffff)), hi = bf2f((u16)(ws[j] >> 16));
      o[j] = cvtpk_bf16((lo * cs[j] - hi * sn[j]) * QSCALE, (hi * cs[j] + lo * sn[j]) * QSCALE);
    }
    u16* qp = &Qh[((size_t)bh * S_LEN + s) * 64 + dg];
    *(uint4*)qp = (uint4){o[0], o[1], o[2], o[3]};
    *(uint4*)(qp + 8) = (uint4){o[4], o[5], o[6], o[7]};
  }
  {
    uint4 a = *(const uint4*)&QKVb[rowbase + 1024];
    uint4 bbu = *(const uint4*)&QKVb[rowbase + 1032];
    unsigned ws[8] = {a.x, a.y, a.z, a.w, bbu.x, bbu.y, bbu.z, bbu.w};
    unsigned o[8];
    #pragma unroll
    for (int j = 0; j < 8; ++j) {
      float lo = bf2f((u16)(ws[j] & 0xffff)), hi = bf2f((u16)(ws[j] >> 16));
      o[j] = cvtpk_bf16(lo * cs[j] - hi * sn[j], hi * cs[j] + lo * sn[j]);
    }
    u16* kp = &Kh[((size_t)bh * S_LEN + s) * 64 + dg];
    *(uint4*)kp = (uint4){o[0], o[1], o[2], o[3]};
    *(uint4*)(kp + 8) = (uint4){o[4], o[5], o[6], o[7]};
  }
  {
    uint4 a = *(const uint4*)&QKVb[rowbase + 2048];
    uint4 bbu = *(const uint4*)&QKVb[rowbase + 2056];
    unsigned ws[8] = {a.x, a.y, a.z, a.w, bbu.x, bbu.y, bbu.z, bbu.w};
    #pragma unroll
    for (int j = 0; j < 8; ++j) {
      Vlds[(dg + 2 * j) * 80 + sr] = (u16)(ws[j] & 0xffff);
      Vlds[(dg + 2 * j + 1) * 80 + sr] = (u16)(ws[j] >> 16);
    }
  }
  __syncthreads();
  {
    int d = tid >> 2, sg = (tid & 3) * 16;
    uint4 v0 = *(const uint4*)&Vlds[d * 80 + sg];
    uint4 v1 = *(const uint4*)&Vlds[d * 80 + sg + 8];
    u16* vp = &Vt[((size_t)bh * 64 + d) * S_LEN + s0 + sg];
    *(uint4*)vp = v0;
    *(uint4*)(vp + 8) = v1;
  }
}

// ---------- flash attention: 8 waves = 4 q-groups x 2 kv-halves, swapped-QK^T 32x32x16,
//            in-register softmax (tree reductions), double-buffered 128-key tiles,
//            end-of-block LSE merge. __launch_bounds__(512,2): natural VGPR (~116)
//            -> 2 blocks/CU (LDS) x 8 waves = 4 waves/SIMD, no spills. ----------
__global__ __launch_bounds__(512, 2) void k_attn(const u16* __restrict__ Qh, const u16* __restrict__ Kh,
                                                 const u16* __restrict__ Vt,
                                                 const float* __restrict__ mask,
                                                 const unsigned char* __restrict__ flags,
                                                 u16* __restrict__ Out) {
  __shared__ __attribute__((aligned(16))) u16 Ks[2][128 * 64];  // 32 KB (reused: O-exchange)
  __shared__ __attribute__((aligned(16))) u16 Vs[2][64 * 128];  // 32 KB (reused: m/l exchange)
  int f = blockIdx.y * gridDim.x + blockIdx.x;  // grid (16, 32)
  int xcd = f & 7, ii = f >> 3;
  int bh = xcd * 4 + (ii >> 4);
  int q0 = (ii & 15) * 128;
  int b = bh >> 4, h = bh & 15;
  int tid = threadIdx.x, lane = tid & 63, w = tid >> 6;
  int wq = w & 3, wh = w >> 2;  // q-group, kv-half
  int l31 = lane & 31, l5 = lane >> 5;

  int qrow = q0 + wq * 32 + l31;
  int qt = qrow >> 6;  // wave-uniform

  bf16x8 qf[4];
  {
    const u16* qp = Qh + ((size_t)bh * S_LEN + qrow) * 64 + l5 * 8;
    #pragma unroll
    for (int dc = 0; dc < 4; ++dc) qf[dc] = *(const bf16x8*)(qp + dc * 16);
  }

  const u16* Kbase = Kh + (size_t)bh * S_LEN * 64;
  const u16* Vbase = Vt + (size_t)bh * 64 * S_LEN;

  int koff_[2], voff_[2];
  #pragma unroll
  for (int i = 0; i < 2; ++i) {
    int s = i * 512 + tid;  // 16B slot in [0,1024)
    int kr = s >> 3, kslot = s & 7;
    koff_[i] = kr * 64 + (kslot ^ (kr & 7)) * 8;
    int vr = s >> 4, vslot = s & 15;
    voff_[i] = vr * S_LEN + (vslot ^ (vr & 15)) * 8;
  }

  float m_run = -1e30f, l_run = 0.f;
  f32x16 oA = {}, oB = {};

  const int NTILE = S_LEN / 128;
  #pragma unroll
  for (int i = 0; i < 2; ++i) {
    gload_lds16(Kbase + koff_[i], &Ks[0][(i * 512 + tid) * 8]);
    gload_lds16(Vbase + voff_[i], &Vs[0][(i * 512 + tid) * 8]);
  }

  int khalf = wh * 64;  // this wave's 64-key half within the 128-key tile

  for (int t = 0; t < NTILE; ++t) {
    int cur = t & 1;
    asm volatile("s_waitcnt vmcnt(0)" ::: "memory");  // tile t landed
    __builtin_amdgcn_s_barrier();                     // all waves past compute(t-1)
    if (t + 1 < NTILE) {                              // stage t+1 under compute(t)
      const u16* kt_ = Kbase + (size_t)(t + 1) * 8192;
      const u16* vt_ = Vbase + (t + 1) * 128;
      #pragma unroll
      for (int i = 0; i < 2; ++i) {
        gload_lds16(kt_ + koff_[i], &Ks[cur ^ 1][(i * 512 + tid) * 8]);
        gload_lds16(vt_ + voff_[i], &Vs[cur ^ 1][(i * 512 + tid) * 8]);
      }
    }

    // S^T = K @ Q^T over this wave's 64-key half
    f32x16 sA = {}, sB = {};
    __builtin_amdgcn_s_setprio(1);
    #pragma unroll
    for (int dc = 0; dc < 4; ++dc) {
      int r0 = khalf + l31, r1 = khalf + 32 + l31;
      int slot = (dc * 2 + l5) ^ (l31 & 7);
      bf16x8 ka0 = *(const bf16x8*)&Ks[cur][r0 * 64 + slot * 8];
      bf16x8 ka1 = *(const bf16x8*)&Ks[cur][r1 * 64 + slot * 8];
      sA = __builtin_amdgcn_mfma_f32_32x32x16_bf16(ka0, qf[dc], sA, 0, 0, 0);
      sB = __builtin_amdgcn_mfma_f32_32x32x16_bf16(ka1, qf[dc], sB, 0, 0, 0);
    }
    __builtin_amdgcn_s_setprio(0);

    int kv0abs = t * 128 + khalf;
    int fl = flags[qt * 32 + (kv0abs >> 6)];
    if (fl) {
      const float* mrow = mask + (size_t)qrow * S_LEN + kv0abs;
      #pragma unroll
      for (int r = 0; r < 16; ++r) {
        int key = (r & 3) + 8 * (r >> 2) + 4 * l5;
        if (mrow[key] < 0.1f) sA[r] = -1e30f;
        if (mrow[key + 32] < 0.1f) sB[r] = -1e30f;
      }
    }

    // tree max (depth ~5 instead of serial 32)
    float mx8[8];
    #pragma unroll
    for (int r = 0; r < 8; ++r)
      mx8[r] = fmaxf(fmaxf(sA[r], sA[r + 8]), fmaxf(sB[r], sB[r + 8]));
    #pragma unroll
    for (int r = 0; r < 4; ++r) mx8[r] = fmaxf(mx8[r], mx8[r + 4]);
    float pm = fmaxf(fmaxf(fmaxf(mx8[0], mx8[1]), fmaxf(mx8[2], mx8[3])), m_run);
    pm = fmaxf(pm, __shfl_xor(pm, 32, 64));
    if (!__all(pm <= m_run + 8.f)) {  // defer-max (log2 units)
      float corr = __builtin_amdgcn_exp2f(m_run - pm);
      m_run = pm;
      l_run *= corr;
      #pragma unroll
      for (int r = 0; r < 16; ++r) { oA[r] *= corr; oB[r] *= corr; }
    }
    #pragma unroll
    for (int r = 0; r < 16; ++r) {
      sA[r] = __builtin_amdgcn_exp2f(sA[r] - m_run);
      sB[r] = __builtin_amdgcn_exp2f(sB[r] - m_run);
    }
    // tree sum
    float t8[8];
    #pragma unroll
    for (int r = 0; r < 8; ++r) t8[r] = (sA[r] + sA[r + 8]) + (sB[r] + sB[r + 8]);
    #pragma unroll
    for (int r = 0; r < 4; ++r) t8[r] += t8[r + 4];
    l_run += (t8[0] + t8[1]) + (t8[2] + t8[3]);

    // P^T -> B-frags; PV: O^T += V^T @ P^T
    __builtin_amdgcn_s_setprio(1);
    #pragma unroll
    for (int kh = 0; kh < 2; ++kh) {
      f32x16 s = kh ? sB : sA;
      #pragma unroll
      for (int c = 0; c < 2; ++c) {
        int base = c * 8;
        unsigned u0 = cvtpk_bf16(s[base + 0], s[base + 1]);
        unsigned u1 = cvtpk_bf16(s[base + 2], s[base + 3]);
        unsigned u2 = cvtpk_bf16(s[base + 4], s[base + 5]);
        unsigned u3 = cvtpk_bf16(s[base + 6], s[base + 7]);
        asm volatile("v_permlane32_swap_b32 %0, %1" : "+v"(u0), "+v"(u2));
        asm volatile("v_permlane32_swap_b32 %0, %1" : "+v"(u1), "+v"(u3));
        int32x4 wds = {(int)u0, (int)u1, (int)u2, (int)u3};
        bf16x8 pb = *(bf16x8*)&wds;
        int kslot = wh * 8 + (kh * 2 + c) * 2 + l5;
        int vr0 = l31, vr1 = 32 + l31;
        bf16x8 va0 = *(const bf16x8*)&Vs[cur][vr0 * 128 + (kslot ^ (vr0 & 15)) * 8];
        bf16x8 va1 = *(const bf16x8*)&Vs[cur][vr1 * 128 + (kslot ^ (vr1 & 15)) * 8];
        oA = __builtin_amdgcn_mfma_f32_32x32x16_bf16(va0, pb, oA, 0, 0, 0);
        oB = __builtin_amdgcn_mfma_f32_32x32x16_bf16(va1, pb, oB, 0, 0, 0);
      }
    }
    __builtin_amdgcn_s_setprio(0);
  }

  // ---- end-of-block merge of the two kv-halves (waves w and w^4) ----
  float l_tot = l_run + __shfl_xor(l_run, 32, 64);
  __syncthreads();  // all compute done; LDS reusable
  float* mlds = (float*)Vs;  // [2][8 waves][64 lanes]
  mlds[w * 64 + lane] = m_run;
  mlds[512 + w * 64 + lane] = l_tot;
  __syncthreads();
  int pw = w ^ 4;
  float pm2 = mlds[pw * 64 + lane];
  float pl2 = mlds[512 + pw * 64 + lane];
  float M = fmaxf(m_run, pm2);
  float wgt = __builtin_amdgcn_exp2f(m_run - M);
  float pwgt = __builtin_amdgcn_exp2f(pm2 - M);
  float denom = l_tot * wgt + pl2 * pwgt;  // symmetric: both waves compute same value
  float* oxc = (float*)Ks;  // [32 regs][256 lanes] transposed -> conflict-free
  if (wh == 1) {
    #pragma unroll
    for (int r = 0; r < 16; ++r) {
      oxc[r * 256 + wq * 64 + lane] = oA[r] * wgt;
      oxc[(16 + r) * 256 + wq * 64 + lane] = oB[r] * wgt;
    }
  }
  __syncthreads();
  if (wh == 0) {
    float inv = 1.f / denom;
    int mrow = qrow * 2 + b;
    u16* op = Out + (size_t)mrow * DM + h * 64;
    #pragma unroll
    for (int db = 0; db < 2; ++db) {
      f32x16 o = db ? oB : oA;
      #pragma unroll
      for (int g = 0; g < 4; ++g) {
        int d0 = db * 32 + 8 * g + 4 * l5;
        ushort4 st;
        st.x = f2bf((o[4 * g + 0] * wgt + oxc[(db * 16 + 4 * g + 0) * 256 + wq * 64 + lane]) * inv);
        st.y = f2bf((o[4 * g + 1] * wgt + oxc[(db * 16 + 4 * g + 1) * 256 + wq * 64 + lane]) * inv);
        st.z = f2bf((o[4 * g + 2] * wgt + oxc[(db * 16 + 4 * g + 2) * 256 + wq * 64 + lane]) * inv);
        st.w = f2bf((o[4 * g + 3] * wgt + oxc[(db * 16 + 4 * g + 3) * 256 + wq * 64 + lane]) * inv);
        *(ushort4*)(op + d0) = st;
      }
    }
  }
}

// ---------- fused LayerNorm: x = addf + bvec + sum of 4 bf16 partials; LN -> Yf (+Yb) ----------
__device__ __forceinline__ float wave_sum(float v) {
  #pragma unroll
  for (int off = 32; off >= 1; off >>= 1) v += __shfl_xor(v, off, 64);
  return v;
}

template <int WB>
__global__ __launch_bounds__(256) void k_lnp(const u16* __restrict__ pb, const float* __restrict__ addf,
                                             const float* __restrict__ bvec,
                                             const float* __restrict__ gw, const float* __restrict__ bw,
                                             float* __restrict__ Yf, u16* __restrict__ Yb) {
  int m = blockIdx.x;
  int tid = threadIdx.x, lane = tid & 63, w = tid >> 6;
  __shared__ float part[4];
  __shared__ float shv[2];
  float4 sc = ((const float4*)(addf + (size_t)m * DM))[tid];
  float4 bv = ((const float4*)bvec)[tid];
  float vx = sc.x + bv.x, vy = sc.y + bv.y, vz = sc.z + bv.z, vw = sc.w + bv.w;
  #pragma unroll
  for (int z = 0; z < 4; ++z) {
    ushort4 qv = ((const ushort4*)(pb + (size_t)z * MROWS * DM + (size_t)m * DM))[tid];
    vx += bf2f(qv.x); vy += bf2f(qv.y); vz += bf2f(qv.z); vw += bf2f(qv.w);
  }
  float s = wave_sum(vx + vy + vz + vw);
  if (lane == 0) part[w] = s;
  __syncthreads();
  if (tid == 0) shv[0] = (part[0] + part[1] + part[2] + part[3]) * (1.f / DM);
  __syncthreads();
  float mu = shv[0];
  float d0 = vx - mu, d1 = vy - mu, d2 = vz - mu, d3 = vw - mu;
  float q = wave_sum(d0 * d0 + d1 * d1 + d2 * d2 + d3 * d3);
  if (lane == 0) part[w] = q;
  __syncthreads();
  if (tid == 0) shv[1] = rsqrtf((part[0] + part[1] + part[2] + part[3]) * (1.f / DM) + 1e-5f);
  __syncthreads();
  float rstd = shv[1];
  float4 g4 = ((const float4*)gw)[tid];
  float4 b4 = ((const float4*)bw)[tid];
  float y0 = d0 * rstd * g4.x + b4.x;
  float y1 = d1 * rstd * g4.y + b4.y;
  float y2 = d2 * rstd * g4.z + b4.z;
  float y3 = d3 * rstd * g4.w + b4.w;
  ((float4*)(Yf + (size_t)m * DM))[tid] = make_float4(y0, y1, y2, y3);
  if (WB) {
    ushort4 o;
    o.x = f2bf(y0); o.y = f2bf(y1); o.z = f2bf(y2); o.w = f2bf(y3);
    ((ushort4*)(Yb + (size_t)m * DM))[tid] = o;
  }
}

extern "C" void kernel_launch(void* const* d_in, const int* in_sizes, int n_in,
                              void* d_out, int out_size, void* d_ws, size_t ws_size,
                              hipStream_t stream) {
  (void)in_sizes; (void)n_in; (void)out_size; (void)ws_size;
  const float* src  = (const float*)d_in[0];
  const float* mask = (const float*)d_in[1];
  const float* Wq = (const float*)d_in[2];  const float* bq  = (const float*)d_in[3];
  const float* Wk = (const float*)d_in[4];  const float* bk  = (const float*)d_in[5];
  const float* Wv = (const float*)d_in[6];  const float* bv  = (const float*)d_in[7];
  const float* Wo = (const float*)d_in[8];  const float* bo  = (const float*)d_in[9];
  const float* W1 = (const float*)d_in[10]; const float* b1  = (const float*)d_in[11];
  const float* W2 = (const float*)d_in[12]; const float* b2  = (const float*)d_in[13];
  const float* g1 = (const float*)d_in[14]; const float* be1 = (const float*)d_in[15];
  const float* g2 = (const float*)d_in[16]; const float* be2 = (const float*)d_in[17];
  float* out = (float*)d_out;

  char* base = (char*)d_ws;
  size_t off = 0;
  auto carve = [&](size_t bytes) -> void* {
    void* r = base + off;
    off += (bytes + 255) & ~(size_t)255;
    return r;
  };
  u16* Wq_t = (u16*)carve(2ull * 1024 * 1024);  // Wq_t/Wk_t/Wv_t contiguous -> fused N=3072 GEMM
  u16* Wk_t = (u16*)carve(2ull * 1024 * 1024);
  u16* Wv_t = (u16*)carve(2ull * 1024 * 1024);
  u16* Wo_t = (u16*)carve(2ull * 1024 * 1024);
  u16* W1_t = (u16*)carve(2ull * 4096 * 1024);
  u16* W2_t = (u16*)carve(2ull * 1024 * 4096);
  u16* Xbf  = (u16*)carve(2ull * 4096 * 1024);
  float* cosT = (float*)carve(4ull * 2048 * 32);
  float* sinT = (float*)carve(4ull * 2048 * 32);
  float* bqkv = (float*)carve(4ull * 3072);
  unsigned char* mflags = (unsigned char*)carve(1024);
  u16* attn_out = (u16*)carve(2ull * 4096 * 1024);
  float* src2f = (float*)carve(4ull * 4096 * 1024);     // dedicated: live LN1 -> LN2
  float* QKV = (float*)carve(4ull * 4096 * 3072);       // 48MB region, multiply reused
  u16* Qh = (u16*)carve(2ull * 32 * 2048 * 64);         // 8MB
  u16* Kh = (u16*)carve(2ull * 32 * 2048 * 64);         // 8MB
  u16* Vt = (u16*)carve(2ull * 32 * 2048 * 64);         // 8MB
  u16* QKVb = (u16*)QKV;
  u16* woPb = (u16*)QKV;
  u16* ff1 = (u16*)QKV;
  u16* ffPb = (u16*)((char*)QKV + 32ull * 1024 * 1024);
  u16* src2b = (u16*)Vt;

  dim3 blk(256);
  dim3 blk5(512);
  k_prep<<<dim3(16384), blk, 0, stream>>>(Wq, Wk, Wv, Wo, W1, W2, Wq_t, Wk_t, Wv_t, Wo_t,
                                          W1_t, W2_t, (const float4*)src, (ushort4*)Xbf);
  k_misc<<<dim3(1292), blk, 0, stream>>>(cosT, sinT, bq, bk, bv, bqkv, mask, mflags);
  k_gemm256<EPI_BF16><<<dim3(12, 16, 1), blk5, 0, stream>>>(Xbf, Wq_t, bqkv, nullptr, QKVb, 4096, 3072, 1024, 3072, 1024);
  k_rope_heads<<<dim3(32, 32), blk, 0, stream>>>(QKVb, cosT, sinT, Qh, Kh, Vt);
  // attention: 512 blocks x 8 waves; (512,2) -> natural VGPR, 2 blocks/CU, 4 waves/SIMD
  k_attn<<<dim3(16, 32), blk5, 0, stream>>>(Qh, Kh, Vt, mask, mflags, attn_out);
  k_gemm256<EPI_PARTB><<<dim3(4, 16, 4), blk5, 0, stream>>>(attn_out, Wo_t, nullptr, nullptr, woPb, 4096, 1024, 1024, 1024, 256);
  k_lnp<1><<<dim3(4096), blk, 0, stream>>>(woPb, src, bo, g1, be1, src2f, src2b);
  k_gemm256<EPI_RELU_BF16><<<dim3(16, 16, 1), blk5, 0, stream>>>(src2b, W1_t, b1, nullptr, ff1, 4096, 4096, 1024, 4096, 1024);
  k_gemm256<EPI_PARTB><<<dim3(4, 16, 4), blk5, 0, stream>>>(ff1, W2_t, nullptr, nullptr, ffPb, 4096, 1024, 4096, 1024, 1024);
  k_lnp<0><<<dim3(4096), blk, 0, stream>>>(ffPb, src2f, b2, g2, be2, out, nullptr);
}

// Round 12
// 283.873 us; speedup vs baseline: 1.0077x; 1.0077x over previous
//
#include <hip/hip_runtime.h>
#include <math.h>

#define S_LEN 2048
#define DM 1024
#define NH 16
#define HD 64
#define DFF 4096
#define MROWS 4096  // S_LEN * 2 batch

typedef unsigned short u16;
typedef __attribute__((ext_vector_type(8))) __bf16 bf16x8;
typedef __attribute__((ext_vector_type(4))) float f32x4;
typedef __attribute__((ext_vector_type(16))) float f32x16;
typedef __attribute__((ext_vector_type(4))) int int32x4;

__device__ __forceinline__ u16 f2bf(float f) {
  unsigned u = __float_as_uint(f);
  unsigned r = (u + 0x7fffu + ((u >> 16) & 1u)) >> 16;  // RNE
  return (u16)r;
}

__device__ __forceinline__ float bf2f(u16 u) {
  return __uint_as_float((unsigned)u << 16);
}

__device__ __forceinline__ unsigned cvtpk_bf16(float lo, float hi) {
  unsigned r;
  asm("v_cvt_pk_bf16_f32 %0, %1, %2" : "=v"(r) : "v"(lo), "v"(hi));
  return r;
}

__device__ __forceinline__ void gload_lds16(const void* g, void* l) {
  __builtin_amdgcn_global_load_lds((__attribute__((address_space(1))) void*)g,
                                   (__attribute__((address_space(3))) void*)l, 16, 0, 0);
}

// ---------- fused preprocessing: 6 weight transposes + src f2bf + rope table
//            + bias concat + mask tile flags (one dispatch) ----------
// flat ranges: [0,4096) Wq/Wk/Wv/Wo, [4096,8192) W1, [8192,12288) W2,
// [12288,16384) src f2bf, [16384,16640) rope table, [16640,16652) cat3,
// [16652,17676) mask flags.
__global__ __launch_bounds__(256) void k_prep(const float* __restrict__ Wq, const float* __restrict__ Wk,
                                              const float* __restrict__ Wv, const float* __restrict__ Wo,
                                              const float* __restrict__ W1, const float* __restrict__ W2,
                                              u16* __restrict__ Wq_t, u16* __restrict__ Wk_t,
                                              u16* __restrict__ Wv_t, u16* __restrict__ Wo_t,
                                              u16* __restrict__ W1_t, u16* __restrict__ W2_t,
                                              const float4* __restrict__ src4, ushort4* __restrict__ Xbf4,
                                              float* __restrict__ cosT, float* __restrict__ sinT,
                                              const float* __restrict__ bq, const float* __restrict__ bk,
                                              const float* __restrict__ bv, float* __restrict__ bqkv,
                                              const float* __restrict__ mask,
                                              unsigned char* __restrict__ flags) {
  int flat = blockIdx.x;
  if (flat >= 16652) {  // mask tile flags
    int local = flat - 16652;
    int kt = local & 31, qt = local >> 5;
    const float* mp = mask + (size_t)(qt * 64) * S_LEN + kt * 64;
    int tr = threadIdx.x >> 2;
    int tc = (threadIdx.x & 3) * 16;
    int ok = 1;
    #pragma unroll
    for (int c = 0; c < 16; c += 4) {
      float4 v = *(const float4*)(mp + (size_t)tr * S_LEN + tc + c);
      ok &= (v.x >= 0.1f) & (v.y >= 0.1f) & (v.z >= 0.1f) & (v.w >= 0.1f);
    }
    ok = __all(ok) ? 1 : 0;
    __shared__ int sh[4];
    if ((threadIdx.x & 63) == 0) sh[threadIdx.x >> 6] = ok;
    __syncthreads();
    if (threadIdx.x == 0) flags[qt * 32 + kt] = (sh[0] & sh[1] & sh[2] & sh[3]) ? 0 : 1;
    return;
  }
  if (flat >= 16640) {  // bias concat
    int i = (flat - 16640) * 256 + threadIdx.x;
    if (i < 3072) bqkv[i] = i < 1024 ? bq[i] : (i < 2048 ? bk[i - 1024] : bv[i - 2048]);
    return;
  }
  if (flat >= 16384) {  // rope cos/sin table
    int idx = (flat - 16384) * 256 + threadIdx.x;
    int s = idx >> 5, i = idx & 31;
    float inv = powf(10000.f, -(float)(2 * i) / 64.f);
    float ang = (float)s * inv;
    cosT[idx] = cosf(ang);
    sinT[idx] = sinf(ang);
    return;
  }
  if (flat >= 12288) {  // src f2bf
    int i = (flat - 12288) * 256 + threadIdx.x;
    float4 v = src4[i];
    ushort4 o;
    o.x = f2bf(v.x); o.y = f2bf(v.y); o.z = f2bf(v.z); o.w = f2bf(v.w);
    Xbf4[i] = o;
    return;
  }
  __shared__ float tile[32][33];
  const float* W;
  u16* Wt;
  int local, nx, K, N;
  if (flat < 4096) {
    int z = flat >> 10;
    W = z == 0 ? Wq : z == 1 ? Wk : z == 2 ? Wv : Wo;
    Wt = z == 0 ? Wq_t : z == 1 ? Wk_t : z == 2 ? Wv_t : Wo_t;
    local = flat & 1023; nx = 32; K = 1024; N = 1024;
  } else if (flat < 8192) {
    W = W1; Wt = W1_t; local = flat - 4096; nx = 128; K = 1024; N = 4096;
  } else {
    W = W2; Wt = W2_t; local = flat - 8192; nx = 32; K = 4096; N = 1024;
  }
  int n0 = (local % nx) * 32, k0 = (local / nx) * 32;
  int tx = threadIdx.x & 31, ty = threadIdx.x >> 5;
  #pragma unroll
  for (int r = ty; r < 32; r += 8) tile[r][tx] = W[(size_t)(k0 + r) * N + n0 + tx];
  __syncthreads();
  #pragma unroll
  for (int r = ty; r < 32; r += 8) Wt[(size_t)(n0 + r) * K + k0 + tx] = f2bf(tile[tx][r]);
}

// ---------- 256x256-tile pipelined bf16 GEMM ----------
enum { EPI_F32 = 0, EPI_RELU_BF16 = 2, EPI_PARTB = 4, EPI_BF16 = 5 };

template <int EPI>
__global__ __launch_bounds__(512, 2) void k_gemm256(const u16* __restrict__ A,
                                                    const u16* __restrict__ Bt,
                                                    const float* __restrict__ bias,
                                                    float* __restrict__ Cf, u16* __restrict__ Cb,
                                                    int M, int N, int K, int ldc, int Kc) {
  __shared__ __attribute__((aligned(16))) u16 As[4][256 * 32];
  __shared__ __attribute__((aligned(16))) u16 Bs[4][256 * 32];

  int nx = gridDim.x;
  int nwg = nx * gridDim.y;
  int flat = blockIdx.y * nx + blockIdx.x;
  int id = (flat & 7) * (nwg >> 3) + (flat >> 3);
  int n0 = (id % nx) * 256;
  int m0 = (id / nx) * 256;
  int kz = blockIdx.z * Kc;

  int tid = threadIdx.x;
  int lane = tid & 63, w = tid >> 6;
  int wm = (w >> 2) * 128, wn = (w & 3) * 64;
  int l15 = lane & 15, l4 = lane >> 4;
  int NT = Kc >> 5;

  const u16* aS[2];
  const u16* bS[2];
  int dslot[2];
  #pragma unroll
  for (int j = 0; j < 2; ++j) {
    int P = j * 512 + tid;
    int r = P >> 2;
    int sl = (P & 3) ^ (r & 3);
    aS[j] = A + (size_t)(m0 + r) * K + kz + sl * 8;
    bS[j] = Bt + (size_t)(n0 + r) * K + kz + sl * 8;
    dslot[j] = j * 512 + w * 64;
  }

  f32x4 acc[8][4] = {};

  #pragma unroll
  for (int t = 0; t < 3; ++t) {
    #pragma unroll
    for (int j = 0; j < 2; ++j) {
      gload_lds16(aS[j] + t * 32, &As[t][dslot[j] * 8]);
      gload_lds16(bS[j] + t * 32, &Bs[t][dslot[j] * 8]);
    }
  }

  for (int t = 0; t < NT; ++t) {
    int buf = t & 3;
    if (t < NT - 2) asm volatile("s_waitcnt vmcnt(8)" ::: "memory");
    else if (t == NT - 2) asm volatile("s_waitcnt vmcnt(4)" ::: "memory");
    else asm volatile("s_waitcnt vmcnt(0)" ::: "memory");
    __builtin_amdgcn_s_barrier();

    if (t + 3 < NT) {
      int tn = t + 3;
      int bn = tn & 3;
      #pragma unroll
      for (int j = 0; j < 2; ++j) {
        gload_lds16(aS[j] + tn * 32, &As[bn][dslot[j] * 8]);
        gload_lds16(bS[j] + tn * 32, &Bs[bn][dslot[j] * 8]);
      }
    }

    bf16x8 af[8], bq[4];
    #pragma unroll
    for (int m = 0; m < 8; ++m) {
      int r = wm + m * 16 + l15;
      af[m] = *(const bf16x8*)&As[buf][r * 32 + (l4 ^ (r & 3)) * 8];
    }
    #pragma unroll
    for (int n = 0; n < 4; ++n) {
      int r = wn + n * 16 + l15;
      bq[n] = *(const bf16x8*)&Bs[buf][r * 32 + (l4 ^ (r & 3)) * 8];
    }
    __builtin_amdgcn_s_setprio(1);
    #pragma unroll
    for (int m = 0; m < 8; ++m)
      #pragma unroll
      for (int n = 0; n < 4; ++n)
        acc[m][n] = __builtin_amdgcn_mfma_f32_16x16x32_bf16(af[m], bq[n], acc[m][n], 0, 0, 0);
    __builtin_amdgcn_s_setprio(0);
  }

  size_t zoff = (size_t)blockIdx.z * M * ldc;
  #pragma unroll
  for (int m = 0; m < 8; ++m) {
    #pragma unroll
    for (int n = 0; n < 4; ++n) {
      int col = n0 + wn + n * 16 + l15;
      float bv = (EPI == EPI_PARTB) ? 0.f : bias[col];
      #pragma unroll
      for (int r = 0; r < 4; ++r) {
        int row = m0 + wm + m * 16 + l4 * 4 + r;
        float v = acc[m][n][r] + bv;
        size_t o = (size_t)row * ldc + col;
        if (EPI == EPI_F32) Cf[o] = v;
        else if (EPI == EPI_RELU_BF16) Cb[o] = f2bf(fmaxf(v, 0.f));
        else if (EPI == EPI_BF16) Cb[o] = f2bf(v);
        else Cb[zoff + o] = f2bf(v);
      }
    }
  }
}

// ---------- RoPE + head-split, vectorized; V transposed through LDS ----------
#define QSCALE 0.180336881f
__global__ __launch_bounds__(256) void k_rope_heads(const u16* __restrict__ QKVb,
                                                    const float* __restrict__ cosT,
                                                    const float* __restrict__ sinT,
                                                    u16* __restrict__ Qh, u16* __restrict__ Kh,
                                                    u16* __restrict__ Vt) {
  __shared__ u16 Vlds[64 * 80];
  int bh = blockIdx.y;
  int s0 = blockIdx.x * 64;
  int b = bh >> 4, h = bh & 15;
  int tid = threadIdx.x;
  int sr = tid >> 2, dg = (tid & 3) * 16;
  int s = s0 + sr;
  size_t rowbase = (size_t)(s * 2 + b) * 3072 + h * 64 + dg;

  float4 c0 = *(const float4*)&cosT[s * 32 + (dg >> 1)];
  float4 c1 = *(const float4*)&cosT[s * 32 + (dg >> 1) + 4];
  float4 sn0 = *(const float4*)&sinT[s * 32 + (dg >> 1)];
  float4 sn1 = *(const float4*)&sinT[s * 32 + (dg >> 1) + 4];
  float cs[8] = {c0.x, c0.y, c0.z, c0.w, c1.x, c1.y, c1.z, c1.w};
  float sn[8] = {sn0.x, sn0.y, sn0.z, sn0.w, sn1.x, sn1.y, sn1.z, sn1.w};

  {
    uint4 a = *(const uint4*)&QKVb[rowbase];
    uint4 bbu = *(const uint4*)&QKVb[rowbase + 8];
    unsigned ws[8] = {a.x, a.y, a.z, a.w, bbu.x, bbu.y, bbu.z, bbu.w};
    unsigned o[8];
    #pragma unroll
    for (int j = 0; j < 8; ++j) {
      float lo = bf2f((u16)(ws[j] & 0xffff)), hi = bf2f((u16)(ws[j] >> 16));
      o[j] = cvtpk_bf16((lo * cs[j] - hi * sn[j]) * QSCALE, (hi * cs[j] + lo * sn[j]) * QSCALE);
    }
    u16* qp = &Qh[((size_t)bh * S_LEN + s) * 64 + dg];
    *(uint4*)qp = (uint4){o[0], o[1], o[2], o[3]};
    *(uint4*)(qp + 8) = (uint4){o[4], o[5], o[6], o[7]};
  }
  {
    uint4 a = *(const uint4*)&QKVb[rowbase + 1024];
    uint4 bbu = *(const uint4*)&QKVb[rowbase + 1032];
    unsigned ws[8] = {a.x, a.y, a.z, a.w, bbu.x, bbu.y, bbu.z, bbu.w};
    unsigned o[8];
    #pragma unroll
    for (int j = 0; j < 8; ++j) {
      float lo = bf2f((u16)(ws[j] & 0xffff)), hi = bf2f((u16)(ws[j] >> 16));
      o[j] = cvtpk_bf16(lo * cs[j] - hi * sn[j], hi * cs[j] + lo * sn[j]);
    }
    u16* kp = &Kh[((size_t)bh * S_LEN + s) * 64 + dg];
    *(uint4*)kp = (uint4){o[0], o[1], o[2], o[3]};
    *(uint4*)(kp + 8) = (uint4){o[4], o[5], o[6], o[7]};
  }
  {
    uint4 a = *(const uint4*)&QKVb[rowbase + 2048];
    uint4 bbu = *(const uint4*)&QKVb[rowbase + 2056];
    unsigned ws[8] = {a.x, a.y, a.z, a.w, bbu.x, bbu.y, bbu.z, bbu.w};
    #pragma unroll
    for (int j = 0; j < 8; ++j) {
      Vlds[(dg + 2 * j) * 80 + sr] = (u16)(ws[j] & 0xffff);
      Vlds[(dg + 2 * j + 1) * 80 + sr] = (u16)(ws[j] >> 16);
    }
  }
  __syncthreads();
  {
    int d = tid >> 2, sg = (tid & 3) * 16;
    uint4 v0 = *(const uint4*)&Vlds[d * 80 + sg];
    uint4 v1 = *(const uint4*)&Vlds[d * 80 + sg + 8];
    u16* vp = &Vt[((size_t)bh * 64 + d) * S_LEN + s0 + sg];
    *(uint4*)vp = v0;
    *(uint4*)(vp + 8) = v1;
  }
}

// ---------- flash attention: 4 waves x 32 q, swapped-QK^T 32x32x16, in-register softmax.
//            KV tiles of 64 keys, 4 LDS buffers, prefetch distance 3,
//            counted vmcnt(8/4/0) + raw s_barrier (T3+T4, mirrors k_gemm256). ----------
__global__ __launch_bounds__(256) void k_attn(const u16* __restrict__ Qh, const u16* __restrict__ Kh,
                                              const u16* __restrict__ Vt,
                                              const float* __restrict__ mask,
                                              const unsigned char* __restrict__ flags,
                                              u16* __restrict__ Out) {
  __shared__ __attribute__((aligned(16))) u16 Ks[4][64 * 64];  // 32 KB
  __shared__ __attribute__((aligned(16))) u16 Vs[4][64 * 64];  // 32 KB
  int f = blockIdx.y * gridDim.x + blockIdx.x;  // grid (16, 32)
  int xcd = f & 7, ii = f >> 3;
  int bh = xcd * 4 + (ii >> 4);
  int q0 = (ii & 15) * 128;
  int b = bh >> 4, h = bh & 15;
  int tid = threadIdx.x, lane = tid & 63, w = tid >> 6;
  int l31 = lane & 31, l5 = lane >> 5;

  int qrow = q0 + w * 32 + l31;
  int qt = qrow >> 6;  // wave-uniform

  bf16x8 qf[4];
  {
    const u16* qp = Qh + ((size_t)bh * S_LEN + qrow) * 64 + l5 * 8;
    #pragma unroll
    for (int dc = 0; dc < 4; ++dc) qf[dc] = *(const bf16x8*)(qp + dc * 16);
  }

  const u16* Kbase = Kh + (size_t)bh * S_LEN * 64;
  const u16* Vbase = Vt + (size_t)bh * 64 * S_LEN;

  // staging: 256 threads x 2 slots of 16B for K and for V per 64-key tile
  int koff_[2], voff_[2], dsl_[2];
  #pragma unroll
  for (int i = 0; i < 2; ++i) {
    int s = i * 256 + tid;  // 16B slot in [0,512)
    dsl_[i] = s;
    int kr = s >> 3, ksl = s & 7;
    koff_[i] = kr * 64 + (ksl ^ (kr & 7)) * 8;
    int vr = s >> 3, vsl = s & 7;
    voff_[i] = vr * S_LEN + (vsl ^ (vr & 7)) * 8;
  }

  float m_run = -1e30f, l_run = 0.f;
  f32x16 oA = {}, oB = {};

  const int NT = S_LEN / 64;  // 32 tiles
  // prologue: stage tiles 0,1,2
  #pragma unroll
  for (int t = 0; t < 3; ++t) {
    #pragma unroll
    for (int i = 0; i < 2; ++i) {
      gload_lds16(Kbase + t * 4096 + koff_[i], &Ks[t][dsl_[i] * 8]);
      gload_lds16(Vbase + t * 64 + voff_[i], &Vs[t][dsl_[i] * 8]);
    }
  }

  for (int t = 0; t < NT; ++t) {
    int cur = t & 3;
    // counted wait: tile t landed when only the newer tiles' loads remain
    if (t < NT - 2) asm volatile("s_waitcnt vmcnt(8)" ::: "memory");
    else if (t == NT - 2) asm volatile("s_waitcnt vmcnt(4)" ::: "memory");
    else asm volatile("s_waitcnt vmcnt(0)" ::: "memory");
    __builtin_amdgcn_s_barrier();  // raw: no drain; all waves past compute(t-1)

    if (t + 3 < NT) {  // stage t+3 into buf[(t+3)&3] = buf[(t-1)&3] (readers done)
      int bn = (t + 3) & 3;
      #pragma unroll
      for (int i = 0; i < 2; ++i) {
        gload_lds16(Kbase + (size_t)(t + 3) * 4096 + koff_[i], &Ks[bn][dsl_[i] * 8]);
        gload_lds16(Vbase + (t + 3) * 64 + voff_[i], &Vs[bn][dsl_[i] * 8]);
      }
    }

    // S^T = K @ Q^T (64 keys)
    f32x16 sA = {}, sB = {};
    __builtin_amdgcn_s_setprio(1);
    #pragma unroll
    for (int dc = 0; dc < 4; ++dc) {
      int r0 = l31, r1 = 32 + l31;
      int slot = dc * 2 + l5;
      bf16x8 ka0 = *(const bf16x8*)&Ks[cur][r0 * 64 + (slot ^ (r0 & 7)) * 8];
      bf16x8 ka1 = *(const bf16x8*)&Ks[cur][r1 * 64 + (slot ^ (r1 & 7)) * 8];
      sA = __builtin_amdgcn_mfma_f32_32x32x16_bf16(ka0, qf[dc], sA, 0, 0, 0);
      sB = __builtin_amdgcn_mfma_f32_32x32x16_bf16(ka1, qf[dc], sB, 0, 0, 0);
    }
    __builtin_amdgcn_s_setprio(0);

    int fl = flags[qt * 32 + t];
    if (fl) {  // slow path (wave-uniform; all-pass tiles skip)
      const float* mrow = mask + (size_t)qrow * S_LEN + t * 64;
      #pragma unroll
      for (int r = 0; r < 16; ++r) {
        int key = (r & 3) + 8 * (r >> 2) + 4 * l5;
        if (mrow[key] < 0.1f) sA[r] = -1e30f;
        if (mrow[key + 32] < 0.1f) sB[r] = -1e30f;
      }
    }

    // tree max
    float mx8[8];
    #pragma unroll
    for (int r = 0; r < 8; ++r)
      mx8[r] = fmaxf(fmaxf(sA[r], sA[r + 8]), fmaxf(sB[r], sB[r + 8]));
    #pragma unroll
    for (int r = 0; r < 4; ++r) mx8[r] = fmaxf(mx8[r], mx8[r + 4]);
    float pm = fmaxf(fmaxf(fmaxf(mx8[0], mx8[1]), fmaxf(mx8[2], mx8[3])), m_run);
    pm = fmaxf(pm, __shfl_xor(pm, 32, 64));
    if (!__all(pm <= m_run + 8.f)) {  // defer-max (log2 units)
      float corr = __builtin_amdgcn_exp2f(m_run - pm);
      m_run = pm;
      l_run *= corr;
      #pragma unroll
      for (int r = 0; r < 16; ++r) { oA[r] *= corr; oB[r] *= corr; }
    }
    #pragma unroll
    for (int r = 0; r < 16; ++r) {
      sA[r] = __builtin_amdgcn_exp2f(sA[r] - m_run);
      sB[r] = __builtin_amdgcn_exp2f(sB[r] - m_run);
    }
    // tree sum
    float t8[8];
    #pragma unroll
    for (int r = 0; r < 8; ++r) t8[r] = (sA[r] + sA[r + 8]) + (sB[r] + sB[r + 8]);
    #pragma unroll
    for (int r = 0; r < 4; ++r) t8[r] += t8[r + 4];
    l_run += (t8[0] + t8[1]) + (t8[2] + t8[3]);

    // P^T -> B-frags; PV: O^T += V^T @ P^T
    __builtin_amdgcn_s_setprio(1);
    #pragma unroll
    for (int kh = 0; kh < 2; ++kh) {
      f32x16 s = kh ? sB : sA;
      #pragma unroll
      for (int c = 0; c < 2; ++c) {
        int base = c * 8;
        unsigned u0 = cvtpk_bf16(s[base + 0], s[base + 1]);
        unsigned u1 = cvtpk_bf16(s[base + 2], s[base + 3]);
        unsigned u2 = cvtpk_bf16(s[base + 4], s[base + 5]);
        unsigned u3 = cvtpk_bf16(s[base + 6], s[base + 7]);
        asm volatile("v_permlane32_swap_b32 %0, %1" : "+v"(u0), "+v"(u2));
        asm volatile("v_permlane32_swap_b32 %0, %1" : "+v"(u1), "+v"(u3));
        int32x4 wds = {(int)u0, (int)u1, (int)u2, (int)u3};
        bf16x8 pb = *(bf16x8*)&wds;
        int kslot = (kh * 2 + c) * 2 + l5;  // 0..7
        int vr0 = l31, vr1 = 32 + l31;
        bf16x8 va0 = *(const bf16x8*)&Vs[cur][vr0 * 64 + (kslot ^ (vr0 & 7)) * 8];
        bf16x8 va1 = *(const bf16x8*)&Vs[cur][vr1 * 64 + (kslot ^ (vr1 & 7)) * 8];
        oA = __builtin_amdgcn_mfma_f32_32x32x16_bf16(va0, pb, oA, 0, 0, 0);
        oB = __builtin_amdgcn_mfma_f32_32x32x16_bf16(va1, pb, oB, 0, 0, 0);
      }
    }
    __builtin_amdgcn_s_setprio(0);
  }

  float l_tot = l_run + __shfl_xor(l_run, 32, 64);
  float inv = 1.f / l_tot;
  int mrow = qrow * 2 + b;
  u16* op = Out + (size_t)mrow * DM + h * 64;
  #pragma unroll
  for (int db = 0; db < 2; ++db) {
    f32x16 o = db ? oB : oA;
    #pragma unroll
    for (int g = 0; g < 4; ++g) {
      int d0 = db * 32 + 8 * g + 4 * l5;
      ushort4 st;
      st.x = f2bf(o[4 * g + 0] * inv);
      st.y = f2bf(o[4 * g + 1] * inv);
      st.z = f2bf(o[4 * g + 2] * inv);
      st.w = f2bf(o[4 * g + 3] * inv);
      *(ushort4*)(op + d0) = st;
    }
  }
}

// ---------- fused LayerNorm: x = addf + bvec + sum of 4 bf16 partials; LN -> Yf (+Yb) ----------
__device__ __forceinline__ float wave_sum(float v) {
  #pragma unroll
  for (int off = 32; off >= 1; off >>= 1) v += __shfl_xor(v, off, 64);
  return v;
}

template <int WB>
__global__ __launch_bounds__(256) void k_lnp(const u16* __restrict__ pb, const float* __restrict__ addf,
                                             const float* __restrict__ bvec,
                                             const float* __restrict__ gw, const float* __restrict__ bw,
                                             float* __restrict__ Yf, u16* __restrict__ Yb) {
  int m = blockIdx.x;
  int tid = threadIdx.x, lane = tid & 63, w = tid >> 6;
  __shared__ float part[4];
  __shared__ float shv[2];
  float4 sc = ((const float4*)(addf + (size_t)m * DM))[tid];
  float4 bv = ((const float4*)bvec)[tid];
  float vx = sc.x + bv.x, vy = sc.y + bv.y, vz = sc.z + bv.z, vw = sc.w + bv.w;
  #pragma unroll
  for (int z = 0; z < 4; ++z) {
    ushort4 qv = ((const ushort4*)(pb + (size_t)z * MROWS * DM + (size_t)m * DM))[tid];
    vx += bf2f(qv.x); vy += bf2f(qv.y); vz += bf2f(qv.z); vw += bf2f(qv.w);
  }
  float s = wave_sum(vx + vy + vz + vw);
  if (lane == 0) part[w] = s;
  __syncthreads();
  if (tid == 0) shv[0] = (part[0] + part[1] + part[2] + part[3]) * (1.f / DM);
  __syncthreads();
  float mu = shv[0];
  float d0 = vx - mu, d1 = vy - mu, d2 = vz - mu, d3 = vw - mu;
  float q = wave_sum(d0 * d0 + d1 * d1 + d2 * d2 + d3 * d3);
  if (lane == 0) part[w] = q;
  __syncthreads();
  if (tid == 0) shv[1] = rsqrtf((part[0] + part[1] + part[2] + part[3]) * (1.f / DM) + 1e-5f);
  __syncthreads();
  float rstd = shv[1];
  float4 g4 = ((const float4*)gw)[tid];
  float4 b4 = ((const float4*)bw)[tid];
  float y0 = d0 * rstd * g4.x + b4.x;
  float y1 = d1 * rstd * g4.y + b4.y;
  float y2 = d2 * rstd * g4.z + b4.z;
  float y3 = d3 * rstd * g4.w + b4.w;
  ((float4*)(Yf + (size_t)m * DM))[tid] = make_float4(y0, y1, y2, y3);
  if (WB) {
    ushort4 o;
    o.x = f2bf(y0); o.y = f2bf(y1); o.z = f2bf(y2); o.w = f2bf(y3);
    ((ushort4*)(Yb + (size_t)m * DM))[tid] = o;
  }
}

extern "C" void kernel_launch(void* const* d_in, const int* in_sizes, int n_in,
                              void* d_out, int out_size, void* d_ws, size_t ws_size,
                              hipStream_t stream) {
  (void)in_sizes; (void)n_in; (void)out_size; (void)ws_size;
  const float* src  = (const float*)d_in[0];
  const float* mask = (const float*)d_in[1];
  const float* Wq = (const float*)d_in[2];  const float* bq  = (const float*)d_in[3];
  const float* Wk = (const float*)d_in[4];  const float* bk  = (const float*)d_in[5];
  const float* Wv = (const float*)d_in[6];  const float* bv  = (const float*)d_in[7];
  const float* Wo = (const float*)d_in[8];  const float* bo  = (const float*)d_in[9];
  const float* W1 = (const float*)d_in[10]; const float* b1  = (const float*)d_in[11];
  const float* W2 = (const float*)d_in[12]; const float* b2  = (const float*)d_in[13];
  const float* g1 = (const float*)d_in[14]; const float* be1 = (const float*)d_in[15];
  const float* g2 = (const float*)d_in[16]; const float* be2 = (const float*)d_in[17];
  float* out = (float*)d_out;

  char* base = (char*)d_ws;
  size_t off = 0;
  auto carve = [&](size_t bytes) -> void* {
    void* r = base + off;
    off += (bytes + 255) & ~(size_t)255;
    return r;
  };
  u16* Wq_t = (u16*)carve(2ull * 1024 * 1024);  // Wq_t/Wk_t/Wv_t contiguous -> fused N=3072 GEMM
  u16* Wk_t = (u16*)carve(2ull * 1024 * 1024);
  u16* Wv_t = (u16*)carve(2ull * 1024 * 1024);
  u16* Wo_t = (u16*)carve(2ull * 1024 * 1024);
  u16* W1_t = (u16*)carve(2ull * 4096 * 1024);
  u16* W2_t = (u16*)carve(2ull * 1024 * 4096);
  u16* Xbf  = (u16*)carve(2ull * 4096 * 1024);
  float* cosT = (float*)carve(4ull * 2048 * 32);
  float* sinT = (float*)carve(4ull * 2048 * 32);
  float* bqkv = (float*)carve(4ull * 3072);
  unsigned char* mflags = (unsigned char*)carve(1024);
  u16* attn_out = (u16*)carve(2ull * 4096 * 1024);
  float* src2f = (float*)carve(4ull * 4096 * 1024);     // dedicated: live LN1 -> LN2
  float* QKV = (float*)carve(4ull * 4096 * 3072);       // 48MB region, multiply reused
  u16* Qh = (u16*)carve(2ull * 32 * 2048 * 64);         // 8MB
  u16* Kh = (u16*)carve(2ull * 32 * 2048 * 64);         // 8MB
  u16* Vt = (u16*)carve(2ull * 32 * 2048 * 64);         // 8MB
  u16* QKVb = (u16*)QKV;
  u16* woPb = (u16*)QKV;
  u16* ff1 = (u16*)QKV;
  u16* ffPb = (u16*)((char*)QKV + 32ull * 1024 * 1024);
  u16* src2b = (u16*)Vt;

  dim3 blk(256);
  dim3 blk5(512);
  // fused preprocessing: 6 transposes + src f2bf + rope table + bias concat + mask flags
  k_prep<<<dim3(17676), blk, 0, stream>>>(Wq, Wk, Wv, Wo, W1, W2, Wq_t, Wk_t, Wv_t, Wo_t,
                                          W1_t, W2_t, (const float4*)src, (ushort4*)Xbf,
                                          cosT, sinT, bq, bk, bv, bqkv, mask, mflags);
  k_gemm256<EPI_BF16><<<dim3(12, 16, 1), blk5, 0, stream>>>(Xbf, Wq_t, bqkv, nullptr, QKVb, 4096, 3072, 1024, 3072, 1024);
  k_rope_heads<<<dim3(32, 32), blk, 0, stream>>>(QKVb, cosT, sinT, Qh, Kh, Vt);
  // attention: 512 blocks x 4 waves, counted-vmcnt 4-buffer pipeline
  k_attn<<<dim3(16, 32), blk, 0, stream>>>(Qh, Kh, Vt, mask, mflags, attn_out);
  k_gemm256<EPI_PARTB><<<dim3(4, 16, 4), blk5, 0, stream>>>(attn_out, Wo_t, nullptr, nullptr, woPb, 4096, 1024, 1024, 1024, 256);
  k_lnp<1><<<dim3(4096), blk, 0, stream>>>(woPb, src, bo, g1, be1, src2f, src2b);
  k_gemm256<EPI_RELU_BF16><<<dim3(16, 16, 1), blk5, 0, stream>>>(src2b, W1_t, b1, nullptr, ff1, 4096, 4096, 1024, 4096, 1024);
  k_gemm256<EPI_PARTB><<<dim3(4, 16, 4), blk5, 0, stream>>>(ff1, W2_t, nullptr, nullptr, ffPb, 4096, 1024, 4096, 1024, 1024);
  k_lnp<0><<<dim3(4096), blk, 0, stream>>>(ffPb, src2f, b2, g2, be2, out, nullptr);
}

// Round 13
// 275.062 us; speedup vs baseline: 1.0400x; 1.0320x over previous
//
#include <hip/hip_runtime.h>
#include <math.h>

#define S_LEN 2048
#define DM 1024
#define NH 16
#define HD 64
#define DFF 4096
#define MROWS 4096  // S_LEN * 2 batch

typedef unsigned short u16;
typedef __attribute__((ext_vector_type(8))) __bf16 bf16x8;
typedef __attribute__((ext_vector_type(4))) float f32x4;
typedef __attribute__((ext_vector_type(16))) float f32x16;
typedef __attribute__((ext_vector_type(4))) int int32x4;

__device__ __forceinline__ u16 f2bf(float f) {
  unsigned u = __float_as_uint(f);
  unsigned r = (u + 0x7fffu + ((u >> 16) & 1u)) >> 16;  // RNE
  return (u16)r;
}

__device__ __forceinline__ float bf2f(u16 u) {
  return __uint_as_float((unsigned)u << 16);
}

__device__ __forceinline__ unsigned cvtpk_bf16(float lo, float hi) {
  unsigned r;
  asm("v_cvt_pk_bf16_f32 %0, %1, %2" : "=v"(r) : "v"(lo), "v"(hi));
  return r;
}

__device__ __forceinline__ void gload_lds16(const void* g, void* l) {
  __builtin_amdgcn_global_load_lds((__attribute__((address_space(1))) void*)g,
                                   (__attribute__((address_space(3))) void*)l, 16, 0, 0);
}

// ---------- fused preprocessing: 6 weight transposes + src f2bf + rope table
//            + bias concat + mask tile flags (one dispatch) ----------
__global__ __launch_bounds__(256) void k_prep(const float* __restrict__ Wq, const float* __restrict__ Wk,
                                              const float* __restrict__ Wv, const float* __restrict__ Wo,
                                              const float* __restrict__ W1, const float* __restrict__ W2,
                                              u16* __restrict__ Wq_t, u16* __restrict__ Wk_t,
                                              u16* __restrict__ Wv_t, u16* __restrict__ Wo_t,
                                              u16* __restrict__ W1_t, u16* __restrict__ W2_t,
                                              const float4* __restrict__ src4, ushort4* __restrict__ Xbf4,
                                              float* __restrict__ cosT, float* __restrict__ sinT,
                                              const float* __restrict__ bq, const float* __restrict__ bk,
                                              const float* __restrict__ bv, float* __restrict__ bqkv,
                                              const float* __restrict__ mask,
                                              unsigned char* __restrict__ flags) {
  int flat = blockIdx.x;
  if (flat >= 16652) {  // mask tile flags
    int local = flat - 16652;
    int kt = local & 31, qt = local >> 5;
    const float* mp = mask + (size_t)(qt * 64) * S_LEN + kt * 64;
    int tr = threadIdx.x >> 2;
    int tc = (threadIdx.x & 3) * 16;
    int ok = 1;
    #pragma unroll
    for (int c = 0; c < 16; c += 4) {
      float4 v = *(const float4*)(mp + (size_t)tr * S_LEN + tc + c);
      ok &= (v.x >= 0.1f) & (v.y >= 0.1f) & (v.z >= 0.1f) & (v.w >= 0.1f);
    }
    ok = __all(ok) ? 1 : 0;
    __shared__ int sh[4];
    if ((threadIdx.x & 63) == 0) sh[threadIdx.x >> 6] = ok;
    __syncthreads();
    if (threadIdx.x == 0) flags[qt * 32 + kt] = (sh[0] & sh[1] & sh[2] & sh[3]) ? 0 : 1;
    return;
  }
  if (flat >= 16640) {  // bias concat
    int i = (flat - 16640) * 256 + threadIdx.x;
    if (i < 3072) bqkv[i] = i < 1024 ? bq[i] : (i < 2048 ? bk[i - 1024] : bv[i - 2048]);
    return;
  }
  if (flat >= 16384) {  // rope cos/sin table
    int idx = (flat - 16384) * 256 + threadIdx.x;
    int s = idx >> 5, i = idx & 31;
    float inv = powf(10000.f, -(float)(2 * i) / 64.f);
    float ang = (float)s * inv;
    cosT[idx] = cosf(ang);
    sinT[idx] = sinf(ang);
    return;
  }
  if (flat >= 12288) {  // src f2bf
    int i = (flat - 12288) * 256 + threadIdx.x;
    float4 v = src4[i];
    ushort4 o;
    o.x = f2bf(v.x); o.y = f2bf(v.y); o.z = f2bf(v.z); o.w = f2bf(v.w);
    Xbf4[i] = o;
    return;
  }
  __shared__ float tile[32][33];
  const float* W;
  u16* Wt;
  int local, nx, K, N;
  if (flat < 4096) {
    int z = flat >> 10;
    W = z == 0 ? Wq : z == 1 ? Wk : z == 2 ? Wv : Wo;
    Wt = z == 0 ? Wq_t : z == 1 ? Wk_t : z == 2 ? Wv_t : Wo_t;
    local = flat & 1023; nx = 32; K = 1024; N = 1024;
  } else if (flat < 8192) {
    W = W1; Wt = W1_t; local = flat - 4096; nx = 128; K = 1024; N = 4096;
  } else {
    W = W2; Wt = W2_t; local = flat - 8192; nx = 32; K = 4096; N = 1024;
  }
  int n0 = (local % nx) * 32, k0 = (local / nx) * 32;
  int tx = threadIdx.x & 31, ty = threadIdx.x >> 5;
  #pragma unroll
  for (int r = ty; r < 32; r += 8) tile[r][tx] = W[(size_t)(k0 + r) * N + n0 + tx];
  __syncthreads();
  #pragma unroll
  for (int r = ty; r < 32; r += 8) Wt[(size_t)(n0 + r) * K + k0 + tx] = f2bf(tile[tx][r]);
}

// ---------- 256x256-tile pipelined bf16 GEMM ----------
enum { EPI_F32 = 0, EPI_RELU_BF16 = 2, EPI_PARTB = 4, EPI_BF16 = 5 };

template <int EPI>
__global__ __launch_bounds__(512, 2) void k_gemm256(const u16* __restrict__ A,
                                                    const u16* __restrict__ Bt,
                                                    const float* __restrict__ bias,
                                                    float* __restrict__ Cf, u16* __restrict__ Cb,
                                                    int M, int N, int K, int ldc, int Kc) {
  __shared__ __attribute__((aligned(16))) u16 As[4][256 * 32];
  __shared__ __attribute__((aligned(16))) u16 Bs[4][256 * 32];

  int nx = gridDim.x;
  int nwg = nx * gridDim.y;
  int flat = blockIdx.y * nx + blockIdx.x;
  int id = (flat & 7) * (nwg >> 3) + (flat >> 3);
  int n0 = (id % nx) * 256;
  int m0 = (id / nx) * 256;
  int kz = blockIdx.z * Kc;

  int tid = threadIdx.x;
  int lane = tid & 63, w = tid >> 6;
  int wm = (w >> 2) * 128, wn = (w & 3) * 64;
  int l15 = lane & 15, l4 = lane >> 4;
  int NT = Kc >> 5;

  const u16* aS[2];
  const u16* bS[2];
  int dslot[2];
  #pragma unroll
  for (int j = 0; j < 2; ++j) {
    int P = j * 512 + tid;
    int r = P >> 2;
    int sl = (P & 3) ^ (r & 3);
    aS[j] = A + (size_t)(m0 + r) * K + kz + sl * 8;
    bS[j] = Bt + (size_t)(n0 + r) * K + kz + sl * 8;
    dslot[j] = j * 512 + w * 64;
  }

  f32x4 acc[8][4] = {};

  #pragma unroll
  for (int t = 0; t < 3; ++t) {
    #pragma unroll
    for (int j = 0; j < 2; ++j) {
      gload_lds16(aS[j] + t * 32, &As[t][dslot[j] * 8]);
      gload_lds16(bS[j] + t * 32, &Bs[t][dslot[j] * 8]);
    }
  }

  for (int t = 0; t < NT; ++t) {
    int buf = t & 3;
    if (t < NT - 2) asm volatile("s_waitcnt vmcnt(8)" ::: "memory");
    else if (t == NT - 2) asm volatile("s_waitcnt vmcnt(4)" ::: "memory");
    else asm volatile("s_waitcnt vmcnt(0)" ::: "memory");
    __builtin_amdgcn_s_barrier();

    if (t + 3 < NT) {
      int tn = t + 3;
      int bn = tn & 3;
      #pragma unroll
      for (int j = 0; j < 2; ++j) {
        gload_lds16(aS[j] + tn * 32, &As[bn][dslot[j] * 8]);
        gload_lds16(bS[j] + tn * 32, &Bs[bn][dslot[j] * 8]);
      }
    }

    bf16x8 af[8], bq[4];
    #pragma unroll
    for (int m = 0; m < 8; ++m) {
      int r = wm + m * 16 + l15;
      af[m] = *(const bf16x8*)&As[buf][r * 32 + (l4 ^ (r & 3)) * 8];
    }
    #pragma unroll
    for (int n = 0; n < 4; ++n) {
      int r = wn + n * 16 + l15;
      bq[n] = *(const bf16x8*)&Bs[buf][r * 32 + (l4 ^ (r & 3)) * 8];
    }
    __builtin_amdgcn_s_setprio(1);
    #pragma unroll
    for (int m = 0; m < 8; ++m)
      #pragma unroll
      for (int n = 0; n < 4; ++n)
        acc[m][n] = __builtin_amdgcn_mfma_f32_16x16x32_bf16(af[m], bq[n], acc[m][n], 0, 0, 0);
    __builtin_amdgcn_s_setprio(0);
  }

  size_t zoff = (size_t)blockIdx.z * M * ldc;
  #pragma unroll
  for (int m = 0; m < 8; ++m) {
    #pragma unroll
    for (int n = 0; n < 4; ++n) {
      int col = n0 + wn + n * 16 + l15;
      float bv = (EPI == EPI_PARTB) ? 0.f : bias[col];
      #pragma unroll
      for (int r = 0; r < 4; ++r) {
        int row = m0 + wm + m * 16 + l4 * 4 + r;
        float v = acc[m][n][r] + bv;
        size_t o = (size_t)row * ldc + col;
        if (EPI == EPI_F32) Cf[o] = v;
        else if (EPI == EPI_RELU_BF16) Cb[o] = f2bf(fmaxf(v, 0.f));
        else if (EPI == EPI_BF16) Cb[o] = f2bf(v);
        else Cb[zoff + o] = f2bf(v);
      }
    }
  }
}

// ---------- RoPE + head-split, vectorized; V transposed through LDS ----------
#define QSCALE 0.180336881f
__global__ __launch_bounds__(256) void k_rope_heads(const u16* __restrict__ QKVb,
                                                    const float* __restrict__ cosT,
                                                    const float* __restrict__ sinT,
                                                    u16* __restrict__ Qh, u16* __restrict__ Kh,
                                                    u16* __restrict__ Vt) {
  __shared__ u16 Vlds[64 * 80];
  int bh = blockIdx.y;
  int s0 = blockIdx.x * 64;
  int b = bh >> 4, h = bh & 15;
  int tid = threadIdx.x;
  int sr = tid >> 2, dg = (tid & 3) * 16;
  int s = s0 + sr;
  size_t rowbase = (size_t)(s * 2 + b) * 3072 + h * 64 + dg;

  float4 c0 = *(const float4*)&cosT[s * 32 + (dg >> 1)];
  float4 c1 = *(const float4*)&cosT[s * 32 + (dg >> 1) + 4];
  float4 sn0 = *(const float4*)&sinT[s * 32 + (dg >> 1)];
  float4 sn1 = *(const float4*)&sinT[s * 32 + (dg >> 1) + 4];
  float cs[8] = {c0.x, c0.y, c0.z, c0.w, c1.x, c1.y, c1.z, c1.w};
  float sn[8] = {sn0.x, sn0.y, sn0.z, sn0.w, sn1.x, sn1.y, sn1.z, sn1.w};

  {
    uint4 a = *(const uint4*)&QKVb[rowbase];
    uint4 bbu = *(const uint4*)&QKVb[rowbase + 8];
    unsigned ws[8] = {a.x, a.y, a.z, a.w, bbu.x, bbu.y, bbu.z, bbu.w};
    unsigned o[8];
    #pragma unroll
    for (int j = 0; j < 8; ++j) {
      float lo = bf2f((u16)(ws[j] & 0xffff)), hi = bf2f((u16)(ws[j] >> 16));
      o[j] = cvtpk_bf16((lo * cs[j] - hi * sn[j]) * QSCALE, (hi * cs[j] + lo * sn[j]) * QSCALE);
    }
    u16* qp = &Qh[((size_t)bh * S_LEN + s) * 64 + dg];
    *(uint4*)qp = (uint4){o[0], o[1], o[2], o[3]};
    *(uint4*)(qp + 8) = (uint4){o[4], o[5], o[6], o[7]};
  }
  {
    uint4 a = *(const uint4*)&QKVb[rowbase + 1024];
    uint4 bbu = *(const uint4*)&QKVb[rowbase + 1032];
    unsigned ws[8] = {a.x, a.y, a.z, a.w, bbu.x, bbu.y, bbu.z, bbu.w};
    unsigned o[8];
    #pragma unroll
    for (int j = 0; j < 8; ++j) {
      float lo = bf2f((u16)(ws[j] & 0xffff)), hi = bf2f((u16)(ws[j] >> 16));
      o[j] = cvtpk_bf16(lo * cs[j] - hi * sn[j], hi * cs[j] + lo * sn[j]);
    }
    u16* kp = &Kh[((size_t)bh * S_LEN + s) * 64 + dg];
    *(uint4*)kp = (uint4){o[0], o[1], o[2], o[3]};
    *(uint4*)(kp + 8) = (uint4){o[4], o[5], o[6], o[7]};
  }
  {
    uint4 a = *(const uint4*)&QKVb[rowbase + 2048];
    uint4 bbu = *(const uint4*)&QKVb[rowbase + 2056];
    unsigned ws[8] = {a.x, a.y, a.z, a.w, bbu.x, bbu.y, bbu.z, bbu.w};
    #pragma unroll
    for (int j = 0; j < 8; ++j) {
      Vlds[(dg + 2 * j) * 80 + sr] = (u16)(ws[j] & 0xffff);
      Vlds[(dg + 2 * j + 1) * 80 + sr] = (u16)(ws[j] >> 16);
    }
  }
  __syncthreads();
  {
    int d = tid >> 2, sg = (tid & 3) * 16;
    uint4 v0 = *(const uint4*)&Vlds[d * 80 + sg];
    uint4 v1 = *(const uint4*)&Vlds[d * 80 + sg + 8];
    u16* vp = &Vt[((size_t)bh * 64 + d) * S_LEN + s0 + sg];
    *(uint4*)vp = v0;
    *(uint4*)(vp + 8) = v1;
  }
}

// ---------- flash attention (R10 structure, unrolled x2 with static buffer index):
//            4 waves x 32 q, swapped-QK^T 32x32x16, in-register softmax (tree),
//            double-buffered 128-key tiles, XCD-grouped heads, setprio on MFMA ----------
__global__ __launch_bounds__(256) void k_attn(const u16* __restrict__ Qh, const u16* __restrict__ Kh,
                                              const u16* __restrict__ Vt,
                                              const float* __restrict__ mask,
                                              const unsigned char* __restrict__ flags,
                                              u16* __restrict__ Out) {
  __shared__ __attribute__((aligned(16))) u16 Ks[2][128 * 64];
  __shared__ __attribute__((aligned(16))) u16 Vs[2][64 * 128];
  int f = blockIdx.y * gridDim.x + blockIdx.x;  // grid (16, 32)
  int xcd = f & 7, ii = f >> 3;
  int bh = xcd * 4 + (ii >> 4);
  int q0 = (ii & 15) * 128;
  int b = bh >> 4, h = bh & 15;
  int tid = threadIdx.x, lane = tid & 63, w = tid >> 6;
  int l31 = lane & 31, l5 = lane >> 5;

  int qrow = q0 + w * 32 + l31;
  int qt = qrow >> 6;  // wave-uniform

  bf16x8 qf[4];
  {
    const u16* qp = Qh + ((size_t)bh * S_LEN + qrow) * 64 + l5 * 8;
    #pragma unroll
    for (int dc = 0; dc < 4; ++dc) qf[dc] = *(const bf16x8*)(qp + dc * 16);
  }

  // per-lane staging sources, advanced incrementally (no per-tile mul)
  const u16* kg[4];
  const u16* vg[4];
  int ksid[4], vsid[4];
  #pragma unroll
  for (int i = 0; i < 4; ++i) {
    int sid = i * 256 + tid;
    ksid[i] = sid;
    vsid[i] = sid;
    int kr = sid >> 3, kslot = sid & 7;
    kg[i] = Kh + (size_t)bh * S_LEN * 64 + (size_t)kr * 64 + (kslot ^ (kr & 7)) * 8;
    int vr = sid >> 4, vslot = sid & 15;
    vg[i] = Vt + (size_t)bh * 64 * S_LEN + (size_t)vr * S_LEN + ((vslot ^ (vr & 15))) * 8;
  }

  float m_run = -1e30f, l_run = 0.f;
  f32x16 oA = {}, oB = {};

  // prologue: stage tile 0 -> buf 0; bump pointers to tile 1
  #pragma unroll
  for (int i = 0; i < 4; ++i) {
    gload_lds16(kg[i], &Ks[0][ksid[i] * 8]);
    gload_lds16(vg[i], &Vs[0][vsid[i] * 8]);
    kg[i] += 128 * 64;
    vg[i] += 128;
  }

#define ATTN_TILE(T, CUR)                                                                     \
  do {                                                                                        \
    asm volatile("s_waitcnt vmcnt(0)" ::: "memory");                                          \
    __builtin_amdgcn_s_barrier();                                                             \
    if ((T) + 1 < 16) {                                                                       \
      _Pragma("unroll")                                                                       \
      for (int i = 0; i < 4; ++i) {                                                           \
        gload_lds16(kg[i], &Ks[(CUR) ^ 1][ksid[i] * 8]);                                      \
        gload_lds16(vg[i], &Vs[(CUR) ^ 1][vsid[i] * 8]);                                      \
        kg[i] += 128 * 64;                                                                    \
        vg[i] += 128;                                                                         \
      }                                                                                       \
    }                                                                                         \
    _Pragma("unroll")                                                                         \
    for (int ksub = 0; ksub < 2; ++ksub) {                                                    \
      int koff = ksub * 64;                                                                   \
      f32x16 sA = {}, sB = {};                                                                \
      __builtin_amdgcn_s_setprio(1);                                                          \
      _Pragma("unroll")                                                                       \
      for (int dc = 0; dc < 4; ++dc) {                                                        \
        int r0 = koff + l31;                                                                  \
        int r1 = koff + 32 + l31;                                                             \
        int slot = (dc * 2 + l5) ^ (l31 & 7);                                                 \
        bf16x8 ka0 = *(const bf16x8*)&Ks[CUR][r0 * 64 + slot * 8];                            \
        bf16x8 ka1 = *(const bf16x8*)&Ks[CUR][r1 * 64 + slot * 8];                            \
        sA = __builtin_amdgcn_mfma_f32_32x32x16_bf16(ka0, qf[dc], sA, 0, 0, 0);               \
        sB = __builtin_amdgcn_mfma_f32_32x32x16_bf16(ka1, qf[dc], sB, 0, 0, 0);               \
      }                                                                                       \
      __builtin_amdgcn_s_setprio(0);                                                          \
      int fl = flags[qt * 32 + (((T) * 128 + koff) >> 6)];                                    \
      if (fl) {                                                                               \
        const float* mrow = mask + (size_t)qrow * S_LEN + (T) * 128 + koff;                   \
        _Pragma("unroll")                                                                     \
        for (int r = 0; r < 16; ++r) {                                                        \
          int key = (r & 3) + 8 * (r >> 2) + 4 * l5;                                          \
          if (mrow[key] < 0.1f) sA[r] = -1e30f;                                               \
          if (mrow[key + 32] < 0.1f) sB[r] = -1e30f;                                          \
        }                                                                                     \
      }                                                                                       \
      float mx8[8];                                                                           \
      _Pragma("unroll")                                                                       \
      for (int r = 0; r < 8; ++r)                                                             \
        mx8[r] = fmaxf(fmaxf(sA[r], sA[r + 8]), fmaxf(sB[r], sB[r + 8]));                     \
      _Pragma("unroll")                                                                       \
      for (int r = 0; r < 4; ++r) mx8[r] = fmaxf(mx8[r], mx8[r + 4]);                         \
      float pm = fmaxf(fmaxf(fmaxf(mx8[0], mx8[1]), fmaxf(mx8[2], mx8[3])), m_run);           \
      pm = fmaxf(pm, __shfl_xor(pm, 32, 64));                                                 \
      if (!__all(pm <= m_run + 8.f)) {                                                        \
        float corr = __builtin_amdgcn_exp2f(m_run - pm);                                      \
        m_run = pm;                                                                           \
        l_run *= corr;                                                                        \
        _Pragma("unroll")                                                                     \
        for (int r = 0; r < 16; ++r) { oA[r] *= corr; oB[r] *= corr; }                        \
      }                                                                                       \
      _Pragma("unroll")                                                                       \
      for (int r = 0; r < 16; ++r) {                                                          \
        sA[r] = __builtin_amdgcn_exp2f(sA[r] - m_run);                                        \
        sB[r] = __builtin_amdgcn_exp2f(sB[r] - m_run);                                        \
      }                                                                                       \
      float t8[8];                                                                            \
      _Pragma("unroll")                                                                       \
      for (int r = 0; r < 8; ++r) t8[r] = (sA[r] + sA[r + 8]) + (sB[r] + sB[r + 8]);          \
      _Pragma("unroll")                                                                       \
      for (int r = 0; r < 4; ++r) t8[r] += t8[r + 4];                                         \
      l_run += (t8[0] + t8[1]) + (t8[2] + t8[3]);                                             \
      __builtin_amdgcn_s_setprio(1);                                                          \
      _Pragma("unroll")                                                                       \
      for (int kh = 0; kh < 2; ++kh) {                                                        \
        f32x16 s = kh ? sB : sA;                                                              \
        _Pragma("unroll")                                                                     \
        for (int c = 0; c < 2; ++c) {                                                         \
          int base = c * 8;                                                                   \
          unsigned u0 = cvtpk_bf16(s[base + 0], s[base + 1]);                                 \
          unsigned u1 = cvtpk_bf16(s[base + 2], s[base + 3]);                                 \
          unsigned u2 = cvtpk_bf16(s[base + 4], s[base + 5]);                                 \
          unsigned u3 = cvtpk_bf16(s[base + 6], s[base + 7]);                                 \
          asm volatile("v_permlane32_swap_b32 %0, %1" : "+v"(u0), "+v"(u2));                  \
          asm volatile("v_permlane32_swap_b32 %0, %1" : "+v"(u1), "+v"(u3));                  \
          int32x4 wds = {(int)u0, (int)u1, (int)u2, (int)u3};                                 \
          bf16x8 pb = *(bf16x8*)&wds;                                                         \
          int kslot = ksub * 8 + (kh * 2 + c) * 2 + l5;                                       \
          int vr0 = l31, vr1 = 32 + l31;                                                      \
          bf16x8 va0 = *(const bf16x8*)&Vs[CUR][vr0 * 128 + (kslot ^ (vr0 & 15)) * 8];        \
          bf16x8 va1 = *(const bf16x8*)&Vs[CUR][vr1 * 128 + (kslot ^ (vr1 & 15)) * 8];        \
          oA = __builtin_amdgcn_mfma_f32_32x32x16_bf16(va0, pb, oA, 0, 0, 0);                 \
          oB = __builtin_amdgcn_mfma_f32_32x32x16_bf16(va1, pb, oB, 0, 0, 0);                 \
        }                                                                                     \
      }                                                                                       \
      __builtin_amdgcn_s_setprio(0);                                                         \
    }                                                                                         \
  } while (0)

  for (int tt = 0; tt < 8; ++tt) {
    ATTN_TILE(2 * tt, 0);
    ATTN_TILE(2 * tt + 1, 1);
  }
#undef ATTN_TILE

  float l_tot = l_run + __shfl_xor(l_run, 32, 64);
  float inv = 1.f / l_tot;
  int mrow = qrow * 2 + b;
  u16* op = Out + (size_t)mrow * DM + h * 64;
  #pragma unroll
  for (int db = 0; db < 2; ++db) {
    f32x16 o = db ? oB : oA;
    #pragma unroll
    for (int g = 0; g < 4; ++g) {
      int d0 = db * 32 + 8 * g + 4 * l5;
      ushort4 st;
      st.x = f2bf(o[4 * g + 0] * inv);
      st.y = f2bf(o[4 * g + 1] * inv);
      st.z = f2bf(o[4 * g + 2] * inv);
      st.w = f2bf(o[4 * g + 3] * inv);
      *(ushort4*)(op + d0) = st;
    }
  }
}

// ---------- fused LayerNorm: x = addf + bvec + sum of 4 bf16 partials; LN -> Yf (+Yb) ----------
__device__ __forceinline__ float wave_sum(float v) {
  #pragma unroll
  for (int off = 32; off >= 1; off >>= 1) v += __shfl_xor(v, off, 64);
  return v;
}

template <int WB>
__global__ __launch_bounds__(256) void k_lnp(const u16* __restrict__ pb, const float* __restrict__ addf,
                                             const float* __restrict__ bvec,
                                             const float* __restrict__ gw, const float* __restrict__ bw,
                                             float* __restrict__ Yf, u16* __restrict__ Yb) {
  int m = blockIdx.x;
  int tid = threadIdx.x, lane = tid & 63, w = tid >> 6;
  __shared__ float part[4];
  __shared__ float shv[2];
  float4 sc = ((const float4*)(addf + (size_t)m * DM))[tid];
  float4 bv = ((const float4*)bvec)[tid];
  float vx = sc.x + bv.x, vy = sc.y + bv.y, vz = sc.z + bv.z, vw = sc.w + bv.w;
  #pragma unroll
  for (int z = 0; z < 4; ++z) {
    ushort4 qv = ((const ushort4*)(pb + (size_t)z * MROWS * DM + (size_t)m * DM))[tid];
    vx += bf2f(qv.x); vy += bf2f(qv.y); vz += bf2f(qv.z); vw += bf2f(qv.w);
  }
  float s = wave_sum(vx + vy + vz + vw);
  if (lane == 0) part[w] = s;
  __syncthreads();
  if (tid == 0) shv[0] = (part[0] + part[1] + part[2] + part[3]) * (1.f / DM);
  __syncthreads();
  float mu = shv[0];
  float d0 = vx - mu, d1 = vy - mu, d2 = vz - mu, d3 = vw - mu;
  float q = wave_sum(d0 * d0 + d1 * d1 + d2 * d2 + d3 * d3);
  if (lane == 0) part[w] = q;
  __syncthreads();
  if (tid == 0) shv[1] = rsqrtf((part[0] + part[1] + part[2] + part[3]) * (1.f / DM) + 1e-5f);
  __syncthreads();
  float rstd = shv[1];
  float4 g4 = ((const float4*)gw)[tid];
  float4 b4 = ((const float4*)bw)[tid];
  float y0 = d0 * rstd * g4.x + b4.x;
  float y1 = d1 * rstd * g4.y + b4.y;
  float y2 = d2 * rstd * g4.z + b4.z;
  float y3 = d3 * rstd * g4.w + b4.w;
  ((float4*)(Yf + (size_t)m * DM))[tid] = make_float4(y0, y1, y2, y3);
  if (WB) {
    ushort4 o;
    o.x = f2bf(y0); o.y = f2bf(y1); o.z = f2bf(y2); o.w = f2bf(y3);
    ((ushort4*)(Yb + (size_t)m * DM))[tid] = o;
  }
}

extern "C" void kernel_launch(void* const* d_in, const int* in_sizes, int n_in,
                              void* d_out, int out_size, void* d_ws, size_t ws_size,
                              hipStream_t stream) {
  (void)in_sizes; (void)n_in; (void)out_size; (void)ws_size;
  const float* src  = (const float*)d_in[0];
  const float* mask = (const float*)d_in[1];
  const float* Wq = (const float*)d_in[2];  const float* bq  = (const float*)d_in[3];
  const float* Wk = (const float*)d_in[4];  const float* bk  = (const float*)d_in[5];
  const float* Wv = (const float*)d_in[6];  const float* bv  = (const float*)d_in[7];
  const float* Wo = (const float*)d_in[8];  const float* bo  = (const float*)d_in[9];
  const float* W1 = (const float*)d_in[10]; const float* b1  = (const float*)d_in[11];
  const float* W2 = (const float*)d_in[12]; const float* b2  = (const float*)d_in[13];
  const float* g1 = (const float*)d_in[14]; const float* be1 = (const float*)d_in[15];
  const float* g2 = (const float*)d_in[16]; const float* be2 = (const float*)d_in[17];
  float* out = (float*)d_out;

  char* base = (char*)d_ws;
  size_t off = 0;
  auto carve = [&](size_t bytes) -> void* {
    void* r = base + off;
    off += (bytes + 255) & ~(size_t)255;
    return r;
  };
  u16* Wq_t = (u16*)carve(2ull * 1024 * 1024);  // Wq_t/Wk_t/Wv_t contiguous -> fused N=3072 GEMM
  u16* Wk_t = (u16*)carve(2ull * 1024 * 1024);
  u16* Wv_t = (u16*)carve(2ull * 1024 * 1024);
  u16* Wo_t = (u16*)carve(2ull * 1024 * 1024);
  u16* W1_t = (u16*)carve(2ull * 4096 * 1024);
  u16* W2_t = (u16*)carve(2ull * 1024 * 4096);
  u16* Xbf  = (u16*)carve(2ull * 4096 * 1024);
  float* cosT = (float*)carve(4ull * 2048 * 32);
  float* sinT = (float*)carve(4ull * 2048 * 32);
  float* bqkv = (float*)carve(4ull * 3072);
  unsigned char* mflags = (unsigned char*)carve(1024);
  u16* attn_out = (u16*)carve(2ull * 4096 * 1024);
  float* src2f = (float*)carve(4ull * 4096 * 1024);     // dedicated: live LN1 -> LN2
  float* QKV = (float*)carve(4ull * 4096 * 3072);       // 48MB region, multiply reused
  u16* Qh = (u16*)carve(2ull * 32 * 2048 * 64);         // 8MB
  u16* Kh = (u16*)carve(2ull * 32 * 2048 * 64);         // 8MB
  u16* Vt = (u16*)carve(2ull * 32 * 2048 * 64);         // 8MB
  u16* QKVb = (u16*)QKV;
  u16* woPb = (u16*)QKV;
  u16* ff1 = (u16*)QKV;
  u16* ffPb = (u16*)((char*)QKV + 32ull * 1024 * 1024);
  u16* src2b = (u16*)Vt;

  dim3 blk(256);
  dim3 blk5(512);
  k_prep<<<dim3(17676), blk, 0, stream>>>(Wq, Wk, Wv, Wo, W1, W2, Wq_t, Wk_t, Wv_t, Wo_t,
                                          W1_t, W2_t, (const float4*)src, (ushort4*)Xbf,
                                          cosT, sinT, bq, bk, bv, bqkv, mask, mflags);
  k_gemm256<EPI_BF16><<<dim3(12, 16, 1), blk5, 0, stream>>>(Xbf, Wq_t, bqkv, nullptr, QKVb, 4096, 3072, 1024, 3072, 1024);
  k_rope_heads<<<dim3(32, 32), blk, 0, stream>>>(QKVb, cosT, sinT, Qh, Kh, Vt);
  // attention: 512 blocks x 4 waves (R10 structure, static-cur unroll)
  k_attn<<<dim3(16, 32), blk, 0, stream>>>(Qh, Kh, Vt, mask, mflags, attn_out);
  k_gemm256<EPI_PARTB><<<dim3(4, 16, 4), blk5, 0, stream>>>(attn_out, Wo_t, nullptr, nullptr, woPb, 4096, 1024, 1024, 1024, 256);
  k_lnp<1><<<dim3(4096), blk, 0, stream>>>(woPb, src, bo, g1, be1, src2f, src2b);
  k_gemm256<EPI_RELU_BF16><<<dim3(16, 16, 1), blk5, 0, stream>>>(src2b, W1_t, b1, nullptr, ff1, 4096, 4096, 1024, 4096, 1024);
  k_gemm256<EPI_PARTB><<<dim3(4, 16, 4), blk5, 0, stream>>>(ff1, W2_t, nullptr, nullptr, ffPb, 4096, 1024, 4096, 1024, 1024);
  k_lnp<0><<<dim3(4096), blk, 0, stream>>>(ffPb, src2f, b2, g2, be2, out, nullptr);
}